// Round 8
// baseline (288.338 us; speedup 1.0000x reference)
//
#include <hip/hip_runtime.h>
#include <hip/hip_fp16.h>

#define N_NODES 100000
#define IN_DIM 256
#define OUT_DIM 64
#define NT 782                 // bins of 128 nodes (dst bins and src bins)
#define NSC 1024               // scatter blocks (4 per CU)
#define SMAX 1600              // staged edges per scatter sub-batch (>= ceil(1.6M/1024))
#define CAP_F 3072             // per-bin capacity (mean 2048, sigma~45 -> +22 sigma)

typedef _Float16 half8 __attribute__((ext_vector_type(8)));
typedef float f32x4 __attribute__((ext_vector_type(4)));

// ---------------- pass 0: zero bin cursors ----------------
__global__ __launch_bounds__(256) void init_kernel(int* __restrict__ cursorD,
                                                   int* __restrict__ cursorS) {
    int i = blockIdx.x * 256 + threadIdx.x;
    if (i < NT) { cursorD[i] = 0; cursorS[i] = 0; }
}

// ---------------- pass 1: dual-binned scatter, NO global per-edge atomics ----------------
// r7 proved this structure (263us total, scatter off the top-5). This round: SMAX
// 3200->1600, NSC 512->1024: LDS 47.6->33 KB => 3->4 blocks/CU, 16 waves/CU, and each
// block's serial phase chain halves. Fixed per-block costs (hist zero, scan) are small.
__global__ __launch_bounds__(256) void scatter_kernel(const int* __restrict__ src,
                                                      const int* __restrict__ dst,
                                                      int* __restrict__ cursorD,
                                                      int* __restrict__ cursorS,
                                                      int* __restrict__ binnedD,
                                                      unsigned char* __restrict__ srcb,
                                                      int E, int chunk) {
    __shared__ int sorted[SMAX];            // 6.4 KB
    __shared__ unsigned short sbin[SMAX];   // 3.2 KB
    __shared__ unsigned char sortedB[SMAX]; // 1.6 KB
    __shared__ unsigned short sbinS[SMAX];  // 3.2 KB
    __shared__ int histD[NT], boffD[NT], resvD[NT];  // 9.4 KB
    __shared__ int histS[NT], boffS[NT], resvS[NT];  // 9.4 KB
    const int t = threadIdx.x, blk = blockIdx.x;
    const int lane = t & 63, wv = t >> 6;
    const int lo = blk * chunk;
    int hiA = lo + chunk; if (hiA > E) hiA = E;
    for (int s0 = lo; s0 < hiA; s0 += SMAX) {
        int m = hiA - s0; if (m > SMAX) m = SMAX;
        for (int i = t; i < NT; i += 256) { histD[i] = 0; histS[i] = 0; }
        __syncthreads();
        // A: dual histogram (coalesced edge reads, LDS atomics only)
        for (int k = t; k < m; k += 256) {
            int s = src[s0 + k], d = dst[s0 + k];
            atomicAdd(&histD[d >> 7], 1);
            atomicAdd(&histS[s >> 7], 1);
        }
        __syncthreads();
        // B1: two 1-wave exclusive scans in parallel (wave0: dst, wave1: src)
        if (wv < 2) {
            int* hsrc = (wv == 0) ? histD : histS;
            int* bdst = (wv == 0) ? boffD : boffS;
            int carry = 0;
            for (int r = 0; r < (NT + 63) / 64; ++r) {
                int i = r * 64 + lane;
                int v = (i < NT) ? hsrc[i] : 0;
                int incl = v;
#pragma unroll
                for (int off = 1; off < 64; off <<= 1) {
                    int y = __shfl_up(incl, off);
                    if (lane >= off) incl += y;
                }
                if (i < NT) bdst[i] = carry + incl - v;
                carry += __shfl(incl, 63);
            }
        }
        __syncthreads();
        // B2: reserve contiguous global ranges; hist becomes place cursor
        for (int i = t; i < NT; i += 256) {
            int hd = histD[i];
            if (hd) resvD[i] = atomicAdd(&cursorD[i], hd);
            int hs = histS[i];
            if (hs) resvS[i] = atomicAdd(&cursorS[i], hs);
            histD[i] = boffD[i];
            histS[i] = boffS[i];
        }
        __syncthreads();
        // C: re-read (L2-hot) and counting-sort both streams into LDS
        for (int k = t; k < m; k += 256) {
            int s = src[s0 + k], d = dst[s0 + k];
            int bd = d >> 7;
            int p = atomicAdd(&histD[bd], 1);
            sorted[p] = (s << 7) | (d & 127);
            sbin[p] = (unsigned short)bd;
            int bs = s >> 7;
            int ps = atomicAdd(&histS[bs], 1);
            sortedB[ps] = (unsigned char)(s & 127);
            sbinS[ps] = (unsigned short)bs;
        }
        __syncthreads();
        // D: burst write-out — consecutive k => consecutive addresses within a bin run
        for (int k = t; k < m; k += 256) {
            int b = sbin[k];
            int loc = resvD[b] + (k - boffD[b]);
            if (loc < CAP_F) binnedD[b * CAP_F + loc] = sorted[k];
            int bs = sbinS[k];
            int locS = resvS[bs] + (k - boffS[bs]);
            if (locS < CAP_F) srcb[bs * CAP_F + locS] = sortedB[k];
        }
        __syncthreads();   // protect LDS for next sub-batch
    }
}

// ---------------- pass 2: per-bin CSR-ify (direct placement) + deg_out ----------------
// r4/r5 lesson: write-coalescing buys nothing measurable -> the LDS sort + linear
// copy-out (3rd pass over the bin + 12 KB LDS) was pure overhead. Direct scattered
// placement within the 12 KB bin region (L2-absorbed). csr no longer aliases binnedD.
__global__ __launch_bounds__(256) void tile_kernel(const int* __restrict__ cursorD,
                                                   const int* __restrict__ cursorS,
                                                   const int* __restrict__ binnedD,
                                                   const unsigned char* __restrict__ srcb,
                                                   int* __restrict__ csr,
                                                   int* __restrict__ offs, int* __restrict__ cnt,
                                                   int* __restrict__ deg_out) {
    __shared__ int h[128], cur[128];
    __shared__ int w0tot;
    const int bin = blockIdx.x, t = threadIdx.x, lane = t & 63;
    if (t < 128) h[t] = 0;
    __syncthreads();

    // ---- dst phase ----
    const int base = bin * CAP_F;
    int m = cursorD[bin]; if (m > CAP_F) m = CAP_F;
    for (int k = t; k < m; k += 256) atomicAdd(&h[binnedD[base + k] & 127], 1);
    __syncthreads();
    int v = (t < 128) ? h[t] : 0;
    int incl = v;
#pragma unroll
    for (int off = 1; off < 64; off <<= 1) {
        int y = __shfl_up(incl, off);
        if (lane >= off) incl += y;
    }
    if (t == 63) w0tot = incl;
    __syncthreads();
    int excl = incl - v + ((t >= 64 && t < 128) ? w0tot : 0);
    if (t < 128) {
        cur[t] = excl;
        int node = bin * 128 + t;
        if (node < N_NODES) { offs[node] = base + excl; cnt[node] = v; }
    }
    __syncthreads();
    for (int k = t; k < m; k += 256) {
        int rec = binnedD[base + k];
        int p = atomicAdd(&cur[rec & 127], 1);
        csr[base + p] = rec >> 7;
    }

    // ---- src phase: byte histogram -> deg_out ----
    __syncthreads();
    if (t < 128) h[t] = 0;
    __syncthreads();
    int ms = cursorS[bin]; if (ms > CAP_F) ms = CAP_F;
    const int sbase = bin * CAP_F;
    for (int k = t; k < ms; k += 256) atomicAdd(&h[srcb[sbase + k]], 1);
    __syncthreads();
    if (t < 128) {
        int node = bin * 128 + t;
        if (node < N_NODES) deg_out[node] = h[t];
    }
}

// ---------------- MFMA GEMM: x = fp16(h) @ fp16(W), row-scaled by rsqrt(deg_out) in epilogue ----------------
#define A_LD 136
__global__ __launch_bounds__(256) void gemm_kernel(const float* __restrict__ hmat,
                                                   const float* __restrict__ W,
                                                   const int* __restrict__ deg_out,
                                                   __half* __restrict__ xh) {
    __shared__ _Float16 sA[64 * A_LD];
    __shared__ _Float16 sB[64 * A_LD];
    const int t = threadIdx.x;
    const int lane = t & 63;
    const int w = t >> 6;
    const int row0 = blockIdx.x * 64;
    const int m0 = (w & 1) * 32;
    const int n0 = (w >> 1) * 32;

    f32x4 acc00 = {0.f, 0.f, 0.f, 0.f}, acc01 = {0.f, 0.f, 0.f, 0.f};
    f32x4 acc10 = {0.f, 0.f, 0.f, 0.f}, acc11 = {0.f, 0.f, 0.f, 0.f};

    for (int khalf = 0; khalf < 2; ++khalf) {
        const int k0 = khalf * 128;
        __syncthreads();
#pragma unroll
        for (int it = 0; it < 8; ++it) {
            int f = t + it * 256;
            int row = f >> 5;
            int c4 = f & 31;
            int grow = row0 + row; if (grow >= N_NODES) grow = N_NODES - 1;
            float4 v = *(const float4*)(hmat + (size_t)grow * IN_DIM + k0 + c4 * 4);
            _Float16 p[4];
            p[0] = (_Float16)v.x; p[1] = (_Float16)v.y;
            p[2] = (_Float16)v.z; p[3] = (_Float16)v.w;
            *(uint2*)&sA[row * A_LD + c4 * 4] = *(uint2*)p;
        }
        {
            int n = t & 63;
            int kk0 = (t >> 6) * 32;
#pragma unroll
            for (int kb = 0; kb < 8; ++kb) {
                _Float16 p[4];
#pragma unroll
                for (int u = 0; u < 4; ++u)
                    p[u] = (_Float16)W[(size_t)(k0 + kk0 + kb * 4 + u) * OUT_DIM + n];
                *(uint2*)&sB[n * A_LD + kk0 + kb * 4] = *(uint2*)p;
            }
        }
        __syncthreads();
#pragma unroll
        for (int kb = 0; kb < 4; ++kb) {
            int koff = kb * 32 + (lane >> 4) * 8;
            half8 a0 = *(const half8*)&sA[(m0 + (lane & 15)) * A_LD + koff];
            half8 a1 = *(const half8*)&sA[(m0 + 16 + (lane & 15)) * A_LD + koff];
            half8 b0 = *(const half8*)&sB[(n0 + (lane & 15)) * A_LD + koff];
            half8 b1 = *(const half8*)&sB[(n0 + 16 + (lane & 15)) * A_LD + koff];
            acc00 = __builtin_amdgcn_mfma_f32_16x16x32_f16(a0, b0, acc00, 0, 0, 0);
            acc01 = __builtin_amdgcn_mfma_f32_16x16x32_f16(a0, b1, acc01, 0, 0, 0);
            acc10 = __builtin_amdgcn_mfma_f32_16x16x32_f16(a1, b0, acc10, 0, 0, 0);
            acc11 = __builtin_amdgcn_mfma_f32_16x16x32_f16(a1, b1, acc11, 0, 0, 0);
        }
    }

    const int col16 = lane & 15;
    const int rq = (lane >> 4) * 4;
#pragma unroll
    for (int mi = 0; mi < 2; ++mi) {
        float nrm[4];
#pragma unroll
        for (int r = 0; r < 4; ++r) {
            int row = row0 + m0 + mi * 16 + rq + r;
            int d = (row < N_NODES) ? deg_out[row] : 1;
            nrm[r] = rsqrtf((float)(d < 1 ? 1 : d));
        }
#pragma unroll
        for (int ni = 0; ni < 2; ++ni) {
            const f32x4 a = (mi == 0) ? (ni == 0 ? acc00 : acc01)
                                      : (ni == 0 ? acc10 : acc11);
            int col = n0 + ni * 16 + col16;
#pragma unroll
            for (int r = 0; r < 4; ++r) {
                int row = row0 + m0 + mi * 16 + rq + r;
                if (row < N_NODES)
                    xh[(size_t)row * OUT_DIM + col] = __float2half(a[r] * nrm[r]);
            }
        }
    }
}

// ---------------- pass 4: aggregate — one wave per node, 8 lanes x 16B per edge row ----------------
__global__ __launch_bounds__(256) void aggregate_kernel(const int* __restrict__ offs,
                                                        const int* __restrict__ cnt,
                                                        const int* __restrict__ csr,
                                                        const __half* __restrict__ xh,
                                                        const float* __restrict__ b,
                                                        float* __restrict__ out) {
    const int t = threadIdx.x;
    const int lane = t & 63;
    const int wid = t >> 6;
    const int node = blockIdx.x * 4 + wid;          // 25000*4 == N_NODES exactly
    const int g = lane >> 3;
    const int c = lane & 7;

    const int start = offs[node];
    const int n = cnt[node];

    float acc[8] = {0.f, 0.f, 0.f, 0.f, 0.f, 0.f, 0.f, 0.f};
    for (int base = 0; base < n; base += 64) {
        int k = base + lane;
        int sidx = (k < n) ? csr[start + k] : 0;
        int m = n - base; if (m > 64) m = 64;
        for (int e0 = 0; e0 < m; e0 += 16) {
            int ea = e0 + g;
            int eb = e0 + 8 + g;
            int sa = __shfl(sidx, ea);
            int sb = __shfl(sidx, eb);
            bool va = ea < m;
            bool vb = eb < m;
            float wa = va ? 1.f : 0.f;
            float wb = vb ? 1.f : 0.f;
            uint4 ra = *(const uint4*)(xh + (size_t)(va ? sa : 0) * OUT_DIM + 8 * c);
            const bool grpb = (e0 + 8) < m;  // wave-uniform
            uint4 rb;
            if (grpb)
                rb = *(const uint4*)(xh + (size_t)(vb ? sb : 0) * OUT_DIM + 8 * c);
            {
                const __half2* hp = (const __half2*)&ra;
#pragma unroll
                for (int p = 0; p < 4; ++p) {
                    float2 f = __half22float2(hp[p]);
                    acc[2 * p]     = fmaf(wa, f.x, acc[2 * p]);
                    acc[2 * p + 1] = fmaf(wa, f.y, acc[2 * p + 1]);
                }
            }
            if (grpb) {
                const __half2* hp = (const __half2*)&rb;
#pragma unroll
                for (int p = 0; p < 4; ++p) {
                    float2 f = __half22float2(hp[p]);
                    acc[2 * p]     = fmaf(wb, f.x, acc[2 * p]);
                    acc[2 * p + 1] = fmaf(wb, f.y, acc[2 * p + 1]);
                }
            }
        }
    }

#pragma unroll
    for (int off = 8; off < 64; off <<= 1) {
#pragma unroll
        for (int p = 0; p < 8; ++p)
            acc[p] += __shfl_xor(acc[p], off);
    }

    if (g == 0) {
        float nrm = rsqrtf((float)(n < 1 ? 1 : n));
        float4 bv0 = *(const float4*)&b[c * 8];
        float4 bv1 = *(const float4*)&b[c * 8 + 4];
        float4 r0, r1;
        r0.x = fmaxf(fmaf(acc[0], nrm, bv0.x), 0.f);
        r0.y = fmaxf(fmaf(acc[1], nrm, bv0.y), 0.f);
        r0.z = fmaxf(fmaf(acc[2], nrm, bv0.z), 0.f);
        r0.w = fmaxf(fmaf(acc[3], nrm, bv0.w), 0.f);
        r1.x = fmaxf(fmaf(acc[4], nrm, bv1.x), 0.f);
        r1.y = fmaxf(fmaf(acc[5], nrm, bv1.y), 0.f);
        r1.z = fmaxf(fmaf(acc[6], nrm, bv1.z), 0.f);
        r1.w = fmaxf(fmaf(acc[7], nrm, bv1.w), 0.f);
        float4* orow = (float4*)(out + (size_t)node * OUT_DIM + c * 8);
        orow[0] = r0;
        orow[1] = r1;
    }
}

extern "C" void kernel_launch(void* const* d_in, const int* in_sizes, int n_in,
                              void* d_out, int out_size, void* d_ws, size_t ws_size,
                              hipStream_t stream) {
    const float* h   = (const float*)d_in[0];
    const int*   src = (const int*)d_in[1];
    const int*   dst = (const int*)d_in[2];
    const float* W   = (const float*)d_in[3];
    const float* b   = (const float*)d_in[4];
    float* out = (float*)d_out;
    const int E = in_sizes[1];
    const int chunkS = (E + NSC - 1) / NSC;

    // workspace layout (16B aligned); everything written before read. ~35.7 MB.
    char* ws = (char*)d_ws;
    int*           cursorD = (int*)(ws);                      // NT ints (pad 3328 B)
    int*           cursorS = (int*)(ws + 3328);               // NT ints (pad 3328 B)
    int*           binnedD = (int*)(ws + 6656);               // NT*CAP_F ints (9.61 MB)
    int*           csr     = (int*)(ws + 9615872);            // NT*CAP_F ints (9.61 MB)
    unsigned char* srcb    = (unsigned char*)(ws + 19225088); // NT*CAP_F bytes (2.4 MB)
    int*           offs    = (int*)(ws + 21627392);           // N ints
    int*           cntA    = (int*)(ws + 22027392);           // N ints
    int*           deg_out = (int*)(ws + 22427392);           // N ints
    __half*        xh      = (__half*)(ws + 22827392);        // N*64 halfs (12.8 MB)

    init_kernel<<<4, 256, 0, stream>>>(cursorD, cursorS);
    scatter_kernel<<<NSC, 256, 0, stream>>>(src, dst, cursorD, cursorS, binnedD, srcb, E, chunkS);
    tile_kernel<<<NT, 256, 0, stream>>>(cursorD, cursorS, binnedD, srcb, csr, offs, cntA, deg_out);
    gemm_kernel<<<(N_NODES + 63) / 64, 256, 0, stream>>>(h, W, deg_out, xh);
    aggregate_kernel<<<N_NODES / 4, 256, 0, stream>>>(offs, cntA, csr, xh, b, out);
}

// Round 9
// 253.623 us; speedup vs baseline: 1.1369x; 1.1369x over previous
//
#include <hip/hip_runtime.h>
#include <hip/hip_fp16.h>

#define N_NODES 100000
#define IN_DIM 256
#define OUT_DIM 64
#define NT 782                 // bins of 128 nodes (dst bins and src bins)
#define NSC 512                // scatter blocks (r7-proven; fixed-overhead bound)
#define SMAX 3200              // staged edges per scatter sub-batch
#define CAP_F 3072             // per-bin capacity (mean 2048, sigma~45 -> +22 sigma)
#define GEMM_BLKS 1563         // (N_NODES+63)/64

typedef _Float16 half8 __attribute__((ext_vector_type(8)));
typedef float f32x4 __attribute__((ext_vector_type(4)));

// ---------------- pass 0: zero bin cursors ----------------
__global__ __launch_bounds__(256) void init_kernel(int* __restrict__ cursorD,
                                                   int* __restrict__ cursorS) {
    int i = blockIdx.x * 256 + threadIdx.x;
    if (i < NT) { cursorD[i] = 0; cursorS[i] = 0; }
}

// ---------------- pass 1 (FUSED): scatter (blocks 0..NSC-1) || gemm (blocks NSC..) ----------------
// gemm is data-independent of scatter; the deg_out epilogue dependency is removed by
// writing xh UNSCALED (norm_src applied per-edge in aggregate via nrmS gather).
// Scatter blocks dispatched first -> all 512 resident immediately (47.6KB LDS, 3 blk/CU);
// gemm blocks fill the remaining slots concurrently. LDS overlaid via one char array.
#define A_LD 136
__global__ __launch_bounds__(256) void fused_kernel(const int* __restrict__ src,
                                                    const int* __restrict__ dst,
                                                    int* __restrict__ cursorD,
                                                    int* __restrict__ cursorS,
                                                    int* __restrict__ binnedD,
                                                    unsigned char* __restrict__ srcb,
                                                    const float* __restrict__ hmat,
                                                    const float* __restrict__ W,
                                                    __half* __restrict__ xh,
                                                    int E, int chunk) {
    __shared__ char smem[47568];
    const int t = threadIdx.x;
    if (blockIdx.x < NSC) {
        // ================= scatter body (r7-exact) =================
        int* sorted            = (int*)(smem);                    // 12800 B
        int* histD             = (int*)(smem + 12800);            // 3128 B
        int* boffD             = (int*)(smem + 15928);
        int* resvD             = (int*)(smem + 19056);
        int* histS             = (int*)(smem + 22184);
        int* boffS             = (int*)(smem + 25312);
        int* resvS             = (int*)(smem + 28440);            // ends 31568
        unsigned short* sbin   = (unsigned short*)(smem + 31568); // 6400 B
        unsigned short* sbinS  = (unsigned short*)(smem + 37968); // 6400 B
        unsigned char* sortedB = (unsigned char*)(smem + 44368);  // 3200 B -> 47568
        const int blk = blockIdx.x;
        const int lane = t & 63, wv = t >> 6;
        const int lo = blk * chunk;
        int hiA = lo + chunk; if (hiA > E) hiA = E;
        for (int s0 = lo; s0 < hiA; s0 += SMAX) {
            int m = hiA - s0; if (m > SMAX) m = SMAX;
            for (int i = t; i < NT; i += 256) { histD[i] = 0; histS[i] = 0; }
            __syncthreads();
            // A: dual histogram
            for (int k = t; k < m; k += 256) {
                int s = src[s0 + k], d = dst[s0 + k];
                atomicAdd(&histD[d >> 7], 1);
                atomicAdd(&histS[s >> 7], 1);
            }
            __syncthreads();
            // B1: two 1-wave exclusive scans (wave0: dst, wave1: src)
            if (wv < 2) {
                int* hsrc = (wv == 0) ? histD : histS;
                int* bdst = (wv == 0) ? boffD : boffS;
                int carry = 0;
                for (int r = 0; r < (NT + 63) / 64; ++r) {
                    int i = r * 64 + lane;
                    int v = (i < NT) ? hsrc[i] : 0;
                    int incl = v;
#pragma unroll
                    for (int off = 1; off < 64; off <<= 1) {
                        int y = __shfl_up(incl, off);
                        if (lane >= off) incl += y;
                    }
                    if (i < NT) bdst[i] = carry + incl - v;
                    carry += __shfl(incl, 63);
                }
            }
            __syncthreads();
            // B2: reserve contiguous global ranges; hist becomes place cursor
            for (int i = t; i < NT; i += 256) {
                int hd = histD[i];
                if (hd) resvD[i] = atomicAdd(&cursorD[i], hd);
                int hs = histS[i];
                if (hs) resvS[i] = atomicAdd(&cursorS[i], hs);
                histD[i] = boffD[i];
                histS[i] = boffS[i];
            }
            __syncthreads();
            // C: re-read (L2-hot) and counting-sort both streams into LDS
            for (int k = t; k < m; k += 256) {
                int s = src[s0 + k], d = dst[s0 + k];
                int bd = d >> 7;
                int p = atomicAdd(&histD[bd], 1);
                sorted[p] = (s << 7) | (d & 127);
                sbin[p] = (unsigned short)bd;
                int bs = s >> 7;
                int ps = atomicAdd(&histS[bs], 1);
                sortedB[ps] = (unsigned char)(s & 127);
                sbinS[ps] = (unsigned short)bs;
            }
            __syncthreads();
            // D: burst write-out
            for (int k = t; k < m; k += 256) {
                int b = sbin[k];
                int loc = resvD[b] + (k - boffD[b]);
                if (loc < CAP_F) binnedD[b * CAP_F + loc] = sorted[k];
                int bs = sbinS[k];
                int locS = resvS[bs] + (k - boffS[bs]);
                if (locS < CAP_F) srcb[bs * CAP_F + locS] = sortedB[k];
            }
            __syncthreads();
        }
    } else {
        // ================= gemm body (UNSCALED epilogue) =================
        _Float16* sA = (_Float16*)(smem);                       // 17408 B
        _Float16* sB = (_Float16*)(smem + 64 * A_LD * 2);       // 17408 B -> 34816
        const int lane = t & 63;
        const int w = t >> 6;
        const int row0 = (blockIdx.x - NSC) * 64;
        const int m0 = (w & 1) * 32;
        const int n0 = (w >> 1) * 32;

        f32x4 acc00 = {0.f, 0.f, 0.f, 0.f}, acc01 = {0.f, 0.f, 0.f, 0.f};
        f32x4 acc10 = {0.f, 0.f, 0.f, 0.f}, acc11 = {0.f, 0.f, 0.f, 0.f};

        for (int khalf = 0; khalf < 2; ++khalf) {
            const int k0 = khalf * 128;
            __syncthreads();
#pragma unroll
            for (int it = 0; it < 8; ++it) {
                int f = t + it * 256;
                int row = f >> 5;
                int c4 = f & 31;
                int grow = row0 + row; if (grow >= N_NODES) grow = N_NODES - 1;
                float4 v = *(const float4*)(hmat + (size_t)grow * IN_DIM + k0 + c4 * 4);
                _Float16 p[4];
                p[0] = (_Float16)v.x; p[1] = (_Float16)v.y;
                p[2] = (_Float16)v.z; p[3] = (_Float16)v.w;
                *(uint2*)&sA[row * A_LD + c4 * 4] = *(uint2*)p;
            }
            {
                int n = t & 63;
                int kk0 = (t >> 6) * 32;
#pragma unroll
                for (int kb = 0; kb < 8; ++kb) {
                    _Float16 p[4];
#pragma unroll
                    for (int u = 0; u < 4; ++u)
                        p[u] = (_Float16)W[(size_t)(k0 + kk0 + kb * 4 + u) * OUT_DIM + n];
                    *(uint2*)&sB[n * A_LD + kk0 + kb * 4] = *(uint2*)p;
                }
            }
            __syncthreads();
#pragma unroll
            for (int kb = 0; kb < 4; ++kb) {
                int koff = kb * 32 + (lane >> 4) * 8;
                half8 a0 = *(const half8*)&sA[(m0 + (lane & 15)) * A_LD + koff];
                half8 a1 = *(const half8*)&sA[(m0 + 16 + (lane & 15)) * A_LD + koff];
                half8 b0 = *(const half8*)&sB[(n0 + (lane & 15)) * A_LD + koff];
                half8 b1 = *(const half8*)&sB[(n0 + 16 + (lane & 15)) * A_LD + koff];
                acc00 = __builtin_amdgcn_mfma_f32_16x16x32_f16(a0, b0, acc00, 0, 0, 0);
                acc01 = __builtin_amdgcn_mfma_f32_16x16x32_f16(a0, b1, acc01, 0, 0, 0);
                acc10 = __builtin_amdgcn_mfma_f32_16x16x32_f16(a1, b0, acc10, 0, 0, 0);
                acc11 = __builtin_amdgcn_mfma_f32_16x16x32_f16(a1, b1, acc11, 0, 0, 0);
            }
        }

        const int col16 = lane & 15;
        const int rq = (lane >> 4) * 4;
#pragma unroll
        for (int mi = 0; mi < 2; ++mi) {
#pragma unroll
            for (int ni = 0; ni < 2; ++ni) {
                const f32x4 a = (mi == 0) ? (ni == 0 ? acc00 : acc01)
                                          : (ni == 0 ? acc10 : acc11);
                int col = n0 + ni * 16 + col16;
#pragma unroll
                for (int r = 0; r < 4; ++r) {
                    int row = row0 + m0 + mi * 16 + rq + r;
                    if (row < N_NODES)
                        xh[(size_t)row * OUT_DIM + col] = __float2half(a[r]);
                }
            }
        }
    }
}

// ---------------- pass 2: per-bin CSR-ify (r7: LDS sort + coalesced, csr aliases binnedD)
//                  + nrmS[node] = rsqrt(deg_out) from the src byte stream ----------------
__global__ __launch_bounds__(256) void tile_kernel(const int* __restrict__ cursorD,
                                                   const int* __restrict__ cursorS,
                                                   const int* __restrict__ binnedD,
                                                   const unsigned char* __restrict__ srcb,
                                                   int* __restrict__ csr,
                                                   int* __restrict__ offs, int* __restrict__ cnt,
                                                   float* __restrict__ nrmS) {
    __shared__ int h[128], cur[128];
    __shared__ int lcsr[CAP_F];   // 12.3 KB
    __shared__ int w0tot;
    const int bin = blockIdx.x, t = threadIdx.x, lane = t & 63;
    if (t < 128) h[t] = 0;
    __syncthreads();

    // ---- dst phase ----
    const int base = bin * CAP_F;
    int m = cursorD[bin]; if (m > CAP_F) m = CAP_F;
    for (int k = t; k < m; k += 256) atomicAdd(&h[binnedD[base + k] & 127], 1);
    __syncthreads();
    int v = (t < 128) ? h[t] : 0;
    int incl = v;
#pragma unroll
    for (int off = 1; off < 64; off <<= 1) {
        int y = __shfl_up(incl, off);
        if (lane >= off) incl += y;
    }
    if (t == 63) w0tot = incl;
    __syncthreads();
    int excl = incl - v + ((t >= 64 && t < 128) ? w0tot : 0);
    if (t < 128) {
        cur[t] = excl;
        int node = bin * 128 + t;
        if (node < N_NODES) { offs[node] = base + excl; cnt[node] = v; }
    }
    __syncthreads();
    for (int k = t; k < m; k += 256) {
        int rec = binnedD[base + k];
        int p = atomicAdd(&cur[rec & 127], 1);
        lcsr[p] = rec >> 7;
    }
    __syncthreads();
    for (int k = t; k < m; k += 256) csr[base + k] = lcsr[k];   // coalesced; aliases binnedD

    // ---- src phase: byte histogram -> nrmS ----
    __syncthreads();
    if (t < 128) h[t] = 0;
    __syncthreads();
    int ms = cursorS[bin]; if (ms > CAP_F) ms = CAP_F;
    const int sbase = bin * CAP_F;
    for (int k = t; k < ms; k += 256) atomicAdd(&h[srcb[sbase + k]], 1);
    __syncthreads();
    if (t < 128) {
        int node = bin * 128 + t;
        if (node < N_NODES) {
            int d = h[t];
            nrmS[node] = rsqrtf((float)(d < 1 ? 1 : d));
        }
    }
}

// ---------------- pass 3: aggregate — per-edge weight = nrmS[src] (gathered, broadcast
// across the 8 lanes sharing an edge: 1 extra transaction per edge) ----------------
__global__ __launch_bounds__(256) void aggregate_kernel(const int* __restrict__ offs,
                                                        const int* __restrict__ cnt,
                                                        const int* __restrict__ csr,
                                                        const float* __restrict__ nrmS,
                                                        const __half* __restrict__ xh,
                                                        const float* __restrict__ b,
                                                        float* __restrict__ out) {
    const int t = threadIdx.x;
    const int lane = t & 63;
    const int wid = t >> 6;
    const int node = blockIdx.x * 4 + wid;          // 25000*4 == N_NODES exactly
    const int g = lane >> 3;
    const int c = lane & 7;

    const int start = offs[node];
    const int n = cnt[node];

    float acc[8] = {0.f, 0.f, 0.f, 0.f, 0.f, 0.f, 0.f, 0.f};
    for (int base = 0; base < n; base += 64) {
        int k = base + lane;
        int sidx = (k < n) ? csr[start + k] : 0;
        int m = n - base; if (m > 64) m = 64;
        for (int e0 = 0; e0 < m; e0 += 16) {
            int ea = e0 + g;
            int eb = e0 + 8 + g;
            int sa = __shfl(sidx, ea);
            int sb = __shfl(sidx, eb);
            bool va = ea < m;
            bool vb = eb < m;
            float wa = va ? nrmS[sa] : 0.f;
            uint4 ra = *(const uint4*)(xh + (size_t)(va ? sa : 0) * OUT_DIM + 8 * c);
            const bool grpb = (e0 + 8) < m;  // wave-uniform
            uint4 rb;
            float wb = 0.f;
            if (grpb) {
                wb = vb ? nrmS[sb] : 0.f;
                rb = *(const uint4*)(xh + (size_t)(vb ? sb : 0) * OUT_DIM + 8 * c);
            }
            {
                const __half2* hp = (const __half2*)&ra;
#pragma unroll
                for (int p = 0; p < 4; ++p) {
                    float2 f = __half22float2(hp[p]);
                    acc[2 * p]     = fmaf(wa, f.x, acc[2 * p]);
                    acc[2 * p + 1] = fmaf(wa, f.y, acc[2 * p + 1]);
                }
            }
            if (grpb) {
                const __half2* hp = (const __half2*)&rb;
#pragma unroll
                for (int p = 0; p < 4; ++p) {
                    float2 f = __half22float2(hp[p]);
                    acc[2 * p]     = fmaf(wb, f.x, acc[2 * p]);
                    acc[2 * p + 1] = fmaf(wb, f.y, acc[2 * p + 1]);
                }
            }
        }
    }

#pragma unroll
    for (int off = 8; off < 64; off <<= 1) {
#pragma unroll
        for (int p = 0; p < 8; ++p)
            acc[p] += __shfl_xor(acc[p], off);
    }

    if (g == 0) {
        float nrm = rsqrtf((float)(n < 1 ? 1 : n));
        float4 bv0 = *(const float4*)&b[c * 8];
        float4 bv1 = *(const float4*)&b[c * 8 + 4];
        float4 r0, r1;
        r0.x = fmaxf(fmaf(acc[0], nrm, bv0.x), 0.f);
        r0.y = fmaxf(fmaf(acc[1], nrm, bv0.y), 0.f);
        r0.z = fmaxf(fmaf(acc[2], nrm, bv0.z), 0.f);
        r0.w = fmaxf(fmaf(acc[3], nrm, bv0.w), 0.f);
        r1.x = fmaxf(fmaf(acc[4], nrm, bv1.x), 0.f);
        r1.y = fmaxf(fmaf(acc[5], nrm, bv1.y), 0.f);
        r1.z = fmaxf(fmaf(acc[6], nrm, bv1.z), 0.f);
        r1.w = fmaxf(fmaf(acc[7], nrm, bv1.w), 0.f);
        float4* orow = (float4*)(out + (size_t)node * OUT_DIM + c * 8);
        orow[0] = r0;
        orow[1] = r1;
    }
}

extern "C" void kernel_launch(void* const* d_in, const int* in_sizes, int n_in,
                              void* d_out, int out_size, void* d_ws, size_t ws_size,
                              hipStream_t stream) {
    const float* h   = (const float*)d_in[0];
    const int*   src = (const int*)d_in[1];
    const int*   dst = (const int*)d_in[2];
    const float* W   = (const float*)d_in[3];
    const float* b   = (const float*)d_in[4];
    float* out = (float*)d_out;
    const int E = in_sizes[1];
    const int chunkS = (E + NSC - 1) / NSC;

    // workspace layout (16B aligned). csr ALIASES binnedD (tile overwrites its own bin
    // region only after its last read). Total ~26 MB.
    char* ws = (char*)d_ws;
    int*           cursorD = (int*)(ws);                      // NT ints (pad 3328 B)
    int*           cursorS = (int*)(ws + 3328);               // NT ints (pad 3328 B)
    int*           binnedD = (int*)(ws + 6656);               // NT*CAP_F ints (9.61 MB)
    int*           csr     = binnedD;                         // alias (see tile_kernel)
    unsigned char* srcb    = (unsigned char*)(ws + 9615872);  // NT*CAP_F bytes (2.4 MB)
    int*           offs    = (int*)(ws + 12018176);           // N ints
    int*           cntA    = (int*)(ws + 12418176);           // N ints
    float*         nrmS    = (float*)(ws + 12818176);         // N floats
    __half*        xh      = (__half*)(ws + 13218176);        // N*64 halfs (12.8 MB)

    init_kernel<<<4, 256, 0, stream>>>(cursorD, cursorS);
    fused_kernel<<<NSC + GEMM_BLKS, 256, 0, stream>>>(src, dst, cursorD, cursorS,
                                                      binnedD, srcb, h, W, xh, E, chunkS);
    tile_kernel<<<NT, 256, 0, stream>>>(cursorD, cursorS, binnedD, srcb, csr, offs, cntA, nrmS);
    aggregate_kernel<<<N_NODES / 4, 256, 0, stream>>>(offs, cntA, csr, nrmS, xh, b, out);
}